// Round 1
// baseline (5796.409 us; speedup 1.0000x reference)
//
#include <hip/hip_runtime.h>
#include <hip/hip_bf16.h>

// Problem constants (fixed by the reference)
#define NN   100000      // nodes
#define NE   1600000     // edges
#define MPAD 100096      // 782 * 128  (padded rows for 128-row GEMM tiles)
#define KD   512         // K = CIN + CIN + H + H
// Output: h_t (NN*128) then c_t (NN*128), fp32.

typedef __attribute__((ext_vector_type(8))) short bf16x8;
typedef __attribute__((ext_vector_type(4))) float f32x4;

// ---- workspace layout (bytes), all 512-aligned ----
#define OFF_DEG   0ull                    // NN f32            (400,000)
#define OFF_NORM  400384ull               // NE f32            (6,400,000)
#define OFF_LX    6800384ull              // NN*128 f32        (51,200,000)
#define OFF_LH    58000384ull             // NN*128 f32        (51,200,000)
#define OFF_F     109200384ull            // MPAD*512 bf16     (102,498,304)
#define OFF_WT    211698688ull            // 512*512 bf16      (524,288)
#define OFF_BIAS  212222976ull            // 512 f32
// total ~212.3 MB

__device__ __forceinline__ unsigned short f2bf(float f) {
    // round-to-nearest-even fp32 -> bf16
    unsigned int u = __float_as_uint(f);
    u += 0x7fffu + ((u >> 16) & 1u);
    return (unsigned short)(u >> 16);
}
__device__ __forceinline__ float sigf(float x)  { return 1.f / (1.f + __expf(-x)); }
__device__ __forceinline__ float tanhf_(float x){ return 1.f - 2.f / (__expf(2.f * x) + 1.f); }

__global__ void zero_kernel(float4* __restrict__ p, int n4) {
    int t = blockIdx.x * 256 + threadIdx.x;
    if (t < n4) p[t] = make_float4(0.f, 0.f, 0.f, 0.f);
}

__global__ void deg_kernel(const int* __restrict__ src, const float* __restrict__ w,
                           float* __restrict__ deg) {
    int e = blockIdx.x * 256 + threadIdx.x;
    if (e < NE) atomicAdd(&deg[src[e]], w[e]);
}

__global__ void norm_kernel(const int* __restrict__ src, const int* __restrict__ dst,
                            const float* __restrict__ w, const float* __restrict__ deg,
                            float* __restrict__ nrm) {
    int e = blockIdx.x * 256 + threadIdx.x;
    if (e >= NE) return;
    float ds = deg[src[e]], dd = deg[dst[e]];
    float a = ds > 0.f ? rsqrtf(ds) : 0.f;
    float b = dd > 0.f ? rsqrtf(dd) : 0.f;
    nrm[e] = -(a * w[e] * b);
}

// 32 threads per edge; each thread does 4 channels of both x->Lx and h->Lh.
__global__ void scatter_kernel(const int* __restrict__ src, const int* __restrict__ dst,
                               const float* __restrict__ nrm,
                               const float* __restrict__ x, const float* __restrict__ hp,
                               float* __restrict__ lx, float* __restrict__ lh) {
    long long t = (long long)blockIdx.x * 256 + threadIdx.x;
    int e = (int)(t >> 5);
    if (e >= NE) return;
    int c = ((int)t & 31) << 2;
    int s = src[e], d = dst[e];
    float nm = nrm[e];
    float4 xv = *(const float4*)(x  + (size_t)s * 128 + c);
    float4 hv = *(const float4*)(hp + (size_t)s * 128 + c);
    float* px = lx + (size_t)d * 128 + c;
    float* ph = lh + (size_t)d * 128 + c;
    atomicAdd(px + 0, nm * xv.x); atomicAdd(px + 1, nm * xv.y);
    atomicAdd(px + 2, nm * xv.z); atomicAdd(px + 3, nm * xv.w);
    atomicAdd(ph + 0, nm * hv.x); atomicAdd(ph + 1, nm * hv.y);
    atomicAdd(ph + 2, nm * hv.z); atomicAdd(ph + 3, nm * hv.w);
}

// F[n][k] bf16: k<128 -> x, <256 -> Lx, <384 -> h_prev, else Lh; pad rows -> 0.
__global__ void pack_f_kernel(const float* __restrict__ x,  const float* __restrict__ lx,
                              const float* __restrict__ hp, const float* __restrict__ lh,
                              unsigned short* __restrict__ F) {
    int t = blockIdx.x * 256 + threadIdx.x;   // 0 .. MPAD*128-1
    int n = t >> 7;
    int rem = t & 127;                        // 4-elem chunk within 512-wide row
    float4 v = make_float4(0.f, 0.f, 0.f, 0.f);
    if (n < NN) {
        const float* s = (rem < 32) ? x : (rem < 64) ? lx : (rem < 96) ? hp : lh;
        int c = (rem & 31) << 2;
        v = *(const float4*)(s + (size_t)n * 128 + c);
    }
    ushort4 o;
    o.x = f2bf(v.x); o.y = f2bf(v.y); o.z = f2bf(v.z); o.w = f2bf(v.w);
    *(ushort4*)(F + (size_t)n * KD + (rem << 2)) = o;
}

// Wt[col][k] (N x K row-major, i.e. B^T), col = 4*h + g (gate-interleaved).
__global__ void pack_w_kernel(const float* __restrict__ Wx0, const float* __restrict__ Wx1,
                              const float* __restrict__ Wh0, const float* __restrict__ Wh1,
                              const float* __restrict__ bx,  const float* __restrict__ bh,
                              unsigned short* __restrict__ Wt, float* __restrict__ bias) {
    int t = blockIdx.x * 256 + threadIdx.x;   // 0 .. 512*512-1
    int col = t >> 9, k = t & 511;
    int h = col >> 2, g = col & 3;
    const float* W; int kk;
    if      (k < 128) { W = Wx0; kk = k; }
    else if (k < 256) { W = Wx1; kk = k - 128; }
    else if (k < 384) { W = Wh0; kk = k - 256; }
    else              { W = Wh1; kk = k - 384; }
    float v = W[((size_t)(g << 7) + kk) * 128 + h];
    Wt[(size_t)col * KD + k] = f2bf(v);
    if (k == 0) bias[col] = bx[(g << 7) + h] + bh[(g << 7) + h];
}

// GEMM: C[m][col] = sum_k F[m][k] * Wt[col][k], 128x128 tile/block, 4 waves 2x2,
// each wave 4x4 of 16x16x32 bf16 MFMA. Fused LSTM epilogue via LDS round-trip.
__launch_bounds__(256)
__global__ void gemm_lstm_kernel(const unsigned short* __restrict__ F,
                                 const unsigned short* __restrict__ Wt,
                                 const float* __restrict__ bias,
                                 const float* __restrict__ c_prev,
                                 float* __restrict__ out) {
    __shared__ __align__(16) union {
        struct { short a[128 * 32]; short b[128 * 32]; } t;   // K-loop tiles (16 KB)
        float c[64 * 132];                                    // epilogue buf (33 KB, +4 pad)
    } sm;

    const int tid  = threadIdx.x;
    const int lane = tid & 63;
    const int wave = tid >> 6;
    const int wm = wave >> 1, wn = wave & 1;
    const int lr = lane & 15, lq = lane >> 4;

    const int ntile = blockIdx.x;             // 0..3   (x fastest: F-tile L2 reuse)
    const int mtile = blockIdx.y;             // 0..781
    const size_t m0 = (size_t)mtile * 128;
    const int n0 = ntile * 128;

    // staging: thread handles 4 x 16B chunks (2 for A, 2 for B)
    const int arow = tid >> 2;                // 0..63
    const int ak   = (tid & 3) << 3;          // k offset in elems: 0,8,16,24
    const short* gA0 = (const short*)F  + (m0 + arow) * KD + ak;
    const short* gA1 = gA0 + (size_t)64 * KD;
    const short* gB0 = (const short*)Wt + (size_t)(n0 + arow) * KD + ak;
    const short* gB1 = gB0 + (size_t)64 * KD;
    short* lA0 = &sm.t.a[arow * 32 + ak];
    short* lA1 = &sm.t.a[(arow + 64) * 32 + ak];
    short* lB0 = &sm.t.b[arow * 32 + ak];
    short* lB1 = &sm.t.b[(arow + 64) * 32 + ak];

    // LDS fragment read addresses (fixed across K iterations)
    const short* pA[4]; const short* pB[4];
#pragma unroll
    for (int i = 0; i < 4; ++i) {
        pA[i] = &sm.t.a[(wm * 64 + i * 16 + lr) * 32 + lq * 8];
        pB[i] = &sm.t.b[(wn * 64 + i * 16 + lr) * 32 + lq * 8];
    }

    f32x4 acc[4][4];
#pragma unroll
    for (int i = 0; i < 4; ++i)
#pragma unroll
        for (int j = 0; j < 4; ++j) acc[i][j] = (f32x4){0.f, 0.f, 0.f, 0.f};

    for (int kt = 0; kt < KD / 32; ++kt) {
        const int ko = kt * 32;
        bf16x8 va0 = *(const bf16x8*)(gA0 + ko);
        bf16x8 va1 = *(const bf16x8*)(gA1 + ko);
        bf16x8 vb0 = *(const bf16x8*)(gB0 + ko);
        bf16x8 vb1 = *(const bf16x8*)(gB1 + ko);
        *(bf16x8*)lA0 = va0;
        *(bf16x8*)lA1 = va1;
        *(bf16x8*)lB0 = vb0;
        *(bf16x8*)lB1 = vb1;
        __syncthreads();
        bf16x8 af[4], bfr[4];
#pragma unroll
        for (int i = 0; i < 4; ++i) af[i]  = *(const bf16x8*)pA[i];
#pragma unroll
        for (int i = 0; i < 4; ++i) bfr[i] = *(const bf16x8*)pB[i];
#pragma unroll
        for (int i = 0; i < 4; ++i)
#pragma unroll
            for (int j = 0; j < 4; ++j)
                acc[i][j] = __builtin_amdgcn_mfma_f32_16x16x32_bf16(af[i], bfr[j], acc[i][j], 0, 0, 0);
        __syncthreads();
    }

    // Epilogue: C/D layout col=lane&15, row=lq*4+r. col = 4*h_local + gate.
    // Two phases of 64 rows through sm.c (64 x 132 padded).
#pragma unroll
    for (int p = 0; p < 2; ++p) {
        if (wm == p) {
#pragma unroll
            for (int i = 0; i < 4; ++i)
#pragma unroll
                for (int j = 0; j < 4; ++j) {
                    int rr = i * 16 + lq * 4;
                    int cc = wn * 64 + j * 16 + lr;
#pragma unroll
                    for (int r = 0; r < 4; ++r)
                        sm.c[(rr + r) * 132 + cc] = acc[i][j][r];
                }
        }
        __syncthreads();
#pragma unroll
        for (int it = 0; it < 8; ++it) {
            int idx = it * 256 + tid;
            int r  = idx >> 5;        // 0..63
            int hh = idx & 31;        // h within tile
            size_t grow = m0 + (size_t)p * 64 + r;
            if (grow < NN) {
                float4 gv = *(const float4*)&sm.c[r * 132 + (hh << 2)];
                float4 bb = *(const float4*)&bias[n0 + (hh << 2)];
                float iv = sigf(gv.x + bb.x);
                float fv = sigf(gv.y + bb.y);
                float gg = tanhf_(gv.z + bb.z);
                float ov = sigf(gv.w + bb.w);
                int hg = (n0 >> 2) + hh;          // global h channel 0..127
                float cp = c_prev[grow * 128 + hg];
                float ct = fv * cp + iv * gg;
                float ht = ov * tanhf_(ct);
                out[grow * 128 + hg] = ht;
                out[(size_t)NN * 128 + grow * 128 + hg] = ct;
            }
        }
        __syncthreads();
    }
}

extern "C" void kernel_launch(void* const* d_in, const int* in_sizes, int n_in,
                              void* d_out, int out_size, void* d_ws, size_t ws_size,
                              hipStream_t stream) {
    const float* x      = (const float*)d_in[0];
    const int*   ei     = (const int*)  d_in[1];
    const float* ew     = (const float*)d_in[2];
    const float* h_prev = (const float*)d_in[3];
    const float* c_prev = (const float*)d_in[4];
    const float* Wx0    = (const float*)d_in[5];
    const float* Wx1    = (const float*)d_in[6];
    const float* Wh0    = (const float*)d_in[7];
    const float* Wh1    = (const float*)d_in[8];
    const float* bx     = (const float*)d_in[9];
    const float* bh     = (const float*)d_in[10];
    float* out = (float*)d_out;

    char* ws = (char*)d_ws;
    float*          deg  = (float*)(ws + OFF_DEG);
    float*          nrm  = (float*)(ws + OFF_NORM);
    float*          lx   = (float*)(ws + OFF_LX);
    float*          lh   = (float*)(ws + OFF_LH);
    unsigned short* F    = (unsigned short*)(ws + OFF_F);
    unsigned short* Wt   = (unsigned short*)(ws + OFF_WT);
    float*          bias = (float*)(ws + OFF_BIAS);

    const int* src = ei;
    const int* dst = ei + NE;

    // zero accumulators (deg; Lx+Lh contiguous)
    zero_kernel<<<(25000 + 255) / 256, 256, 0, stream>>>((float4*)deg, 25000);
    zero_kernel<<<(6400000 + 255) / 256, 256, 0, stream>>>((float4*)lx, 6400000);

    deg_kernel <<<(NE + 255) / 256, 256, 0, stream>>>(src, ew, deg);
    norm_kernel<<<(NE + 255) / 256, 256, 0, stream>>>(src, dst, ew, deg, nrm);
    scatter_kernel<<<NE * 32 / 256, 256, 0, stream>>>(src, dst, nrm, x, h_prev, lx, lh);

    pack_f_kernel<<<MPAD * 128 / 256, 256, 0, stream>>>(x, lx, h_prev, lh, F);
    pack_w_kernel<<<512 * 512 / 256, 256, 0, stream>>>(Wx0, Wx1, Wh0, Wh1, bx, bh, Wt, bias);

    gemm_lstm_kernel<<<dim3(4, MPAD / 128), 256, 0, stream>>>(F, Wt, bias, c_prev, out);
}

// Round 2
// 983.312 us; speedup vs baseline: 5.8948x; 5.8948x over previous
//
#include <hip/hip_runtime.h>
#include <hip/hip_bf16.h>

// Problem constants (fixed by the reference)
#define NN   100000      // nodes
#define NE   1600000     // edges
#define MPAD 100096      // 782 * 128  (padded rows for 128-row GEMM tiles)
#define KD   512         // K = CIN + CIN + H + H
// Output: h_t (NN*128) then c_t (NN*128), fp32.

typedef __attribute__((ext_vector_type(8))) short bf16x8;
typedef __attribute__((ext_vector_type(4))) float f32x4;

// ---- workspace layout (bytes) ----
// deg / cnt / cursor are contiguous and zeroed in one launch.
#define OFF_DEG    0ull            // NN f32      (400,000 -> pad 400,384)
#define OFF_CNT    400384ull       // NN i32
#define OFF_CUR    800768ull       // NN i32
#define OFF_ROWPTR 1201152ull      // (NN+1) i32
#define OFF_CSRS   1601536ull      // NE i32      (6,400,000)
#define OFF_CSRN   8001536ull      // NE f32      (6,400,000)
#define OFF_F      14401536ull     // MPAD*512 bf16 (102,498,304)
#define OFF_WT     116899840ull    // 512*512 bf16
#define OFF_BIAS   117424128ull    // 512 f32
// total ~117.5 MB

__device__ __forceinline__ unsigned short f2bf(float f) {
    unsigned int u = __float_as_uint(f);
    u += 0x7fffu + ((u >> 16) & 1u);
    return (unsigned short)(u >> 16);
}
__device__ __forceinline__ float sigf(float x)  { return 1.f / (1.f + __expf(-x)); }
__device__ __forceinline__ float tanhf_(float x){ return 1.f - 2.f / (__expf(2.f * x) + 1.f); }

__global__ void zero_kernel(float4* __restrict__ p, int n4) {
    int t = blockIdx.x * 256 + threadIdx.x;
    if (t < n4) p[t] = make_float4(0.f, 0.f, 0.f, 0.f);
}

__global__ void deg_kernel(const int* __restrict__ src, const float* __restrict__ w,
                           float* __restrict__ deg) {
    int e = blockIdx.x * 256 + threadIdx.x;
    if (e < NE) atomicAdd(&deg[src[e]], w[e]);
}

__global__ void hist_kernel(const int* __restrict__ dst, int* __restrict__ cnt) {
    int e = blockIdx.x * 256 + threadIdx.x;
    if (e < NE) atomicAdd(&cnt[dst[e]], 1);
}

// Single-block scan: 1024 threads, each owns a chunk of ~98 counters.
__global__ void scan_kernel(const int* __restrict__ cnt, int* __restrict__ rowptr) {
    __shared__ int sums[1024];
    const int T = 1024;
    const int chunk = (NN + T - 1) / T;            // 98
    int t = threadIdx.x;
    int lo = t * chunk;
    int hi = lo + chunk; if (hi > NN) hi = NN;
    int s = 0;
    for (int i = lo; i < hi; ++i) s += cnt[i];
    sums[t] = s;
    __syncthreads();
    for (int off = 1; off < T; off <<= 1) {
        int v = (t >= off) ? sums[t - off] : 0;
        __syncthreads();
        sums[t] += v;
        __syncthreads();
    }
    int base = (t == 0) ? 0 : sums[t - 1];
    for (int i = lo; i < hi; ++i) { rowptr[i] = base; base += cnt[i]; }
    if (t == T - 1) rowptr[NN] = sums[T - 1];
}

// CSR fill: compute norm inline, place (src, norm) at rowptr[dst]+cursor[dst]++
__global__ void fill_kernel(const int* __restrict__ src, const int* __restrict__ dst,
                            const float* __restrict__ w, const float* __restrict__ deg,
                            const int* __restrict__ rowptr, int* __restrict__ cursor,
                            int* __restrict__ csr_src, float* __restrict__ csr_nrm) {
    int e = blockIdx.x * 256 + threadIdx.x;
    if (e >= NE) return;
    int s = src[e], d = dst[e];
    float ds = deg[s], dd = deg[d];
    float a = ds > 0.f ? rsqrtf(ds) : 0.f;
    float b = dd > 0.f ? rsqrtf(dd) : 0.f;
    int pos = rowptr[d] + atomicAdd(&cursor[d], 1);
    csr_src[pos] = s;
    csr_nrm[pos] = -(a * w[e] * b);
}

// One wave per node. Lanes 0-31: x -> (F cols [0,128) self, [128,256) Lx);
// lanes 32-63: h_prev -> (cols [256,384) self, [384,512) Lh).
// Accumulate Lx/Lh in registers (no atomics), write F row directly in bf16.
__launch_bounds__(256)
__global__ void gather_pack_kernel(const int* __restrict__ rowptr,
                                   const int* __restrict__ csr_src,
                                   const float* __restrict__ csr_nrm,
                                   const float* __restrict__ x, const float* __restrict__ hp,
                                   unsigned short* __restrict__ F) {
    int node = (blockIdx.x * 256 + threadIdx.x) >> 6;
    int lane = threadIdx.x & 63;
    if (node >= MPAD) return;
    const int c4 = (lane & 31) << 2;
    const int segS = (lane < 32) ? 0 : 256;
    unsigned short* Frow = F + (size_t)node * KD;
    if (node >= NN) {  // pad rows -> zeros
        *(ushort4*)(Frow + segS + c4)       = make_ushort4(0, 0, 0, 0);
        *(ushort4*)(Frow + segS + 128 + c4) = make_ushort4(0, 0, 0, 0);
        return;
    }
    const float* base_in = (lane < 32) ? x : hp;
    int lo = rowptr[node], hi = rowptr[node + 1];
    float4 acc = make_float4(0.f, 0.f, 0.f, 0.f);
    for (int e = lo; e < hi; ++e) {
        int s    = csr_src[e];
        float nm = csr_nrm[e];
        float4 v = *(const float4*)(base_in + (size_t)s * 128 + c4);
        acc.x += nm * v.x; acc.y += nm * v.y;
        acc.z += nm * v.z; acc.w += nm * v.w;
    }
    float4 self = *(const float4*)(base_in + (size_t)node * 128 + c4);
    *(ushort4*)(Frow + segS + c4) =
        make_ushort4(f2bf(self.x), f2bf(self.y), f2bf(self.z), f2bf(self.w));
    *(ushort4*)(Frow + segS + 128 + c4) =
        make_ushort4(f2bf(acc.x), f2bf(acc.y), f2bf(acc.z), f2bf(acc.w));
}

// Wt[col][k] (N x K row-major, i.e. B^T), col = 4*h + g (gate-interleaved).
__global__ void pack_w_kernel(const float* __restrict__ Wx0, const float* __restrict__ Wx1,
                              const float* __restrict__ Wh0, const float* __restrict__ Wh1,
                              const float* __restrict__ bx,  const float* __restrict__ bh,
                              unsigned short* __restrict__ Wt, float* __restrict__ bias) {
    int t = blockIdx.x * 256 + threadIdx.x;   // 0 .. 512*512-1
    int col = t >> 9, k = t & 511;
    int h = col >> 2, g = col & 3;
    const float* W; int kk;
    if      (k < 128) { W = Wx0; kk = k; }
    else if (k < 256) { W = Wx1; kk = k - 128; }
    else if (k < 384) { W = Wh0; kk = k - 256; }
    else              { W = Wh1; kk = k - 384; }
    float v = W[((size_t)(g << 7) + kk) * 128 + h];
    Wt[(size_t)col * KD + k] = f2bf(v);
    if (k == 0) bias[col] = bx[(g << 7) + h] + bh[(g << 7) + h];
}

// GEMM: C[m][col] = sum_k F[m][k] * Wt[col][k], 128x128 tile/block, 4 waves 2x2,
// each wave 4x4 of 16x16x32 bf16 MFMA. Fused LSTM epilogue via LDS round-trip.
__launch_bounds__(256)
__global__ void gemm_lstm_kernel(const unsigned short* __restrict__ F,
                                 const unsigned short* __restrict__ Wt,
                                 const float* __restrict__ bias,
                                 const float* __restrict__ c_prev,
                                 float* __restrict__ out) {
    __shared__ __align__(16) union {
        struct { short a[128 * 32]; short b[128 * 32]; } t;   // K-loop tiles (16 KB)
        float c[64 * 132];                                    // epilogue buf (33 KB)
    } sm;

    const int tid  = threadIdx.x;
    const int lane = tid & 63;
    const int wave = tid >> 6;
    const int wm = wave >> 1, wn = wave & 1;
    const int lr = lane & 15, lq = lane >> 4;

    const int ntile = blockIdx.x;             // 0..3
    const int mtile = blockIdx.y;             // 0..781
    const size_t m0 = (size_t)mtile * 128;
    const int n0 = ntile * 128;

    const int arow = tid >> 2;                // 0..63
    const int ak   = (tid & 3) << 3;
    const short* gA0 = (const short*)F  + (m0 + arow) * KD + ak;
    const short* gA1 = gA0 + (size_t)64 * KD;
    const short* gB0 = (const short*)Wt + (size_t)(n0 + arow) * KD + ak;
    const short* gB1 = gB0 + (size_t)64 * KD;
    short* lA0 = &sm.t.a[arow * 32 + ak];
    short* lA1 = &sm.t.a[(arow + 64) * 32 + ak];
    short* lB0 = &sm.t.b[arow * 32 + ak];
    short* lB1 = &sm.t.b[(arow + 64) * 32 + ak];

    const short* pA[4]; const short* pB[4];
#pragma unroll
    for (int i = 0; i < 4; ++i) {
        pA[i] = &sm.t.a[(wm * 64 + i * 16 + lr) * 32 + lq * 8];
        pB[i] = &sm.t.b[(wn * 64 + i * 16 + lr) * 32 + lq * 8];
    }

    f32x4 acc[4][4];
#pragma unroll
    for (int i = 0; i < 4; ++i)
#pragma unroll
        for (int j = 0; j < 4; ++j) acc[i][j] = (f32x4){0.f, 0.f, 0.f, 0.f};

    for (int kt = 0; kt < KD / 32; ++kt) {
        const int ko = kt * 32;
        bf16x8 va0 = *(const bf16x8*)(gA0 + ko);
        bf16x8 va1 = *(const bf16x8*)(gA1 + ko);
        bf16x8 vb0 = *(const bf16x8*)(gB0 + ko);
        bf16x8 vb1 = *(const bf16x8*)(gB1 + ko);
        *(bf16x8*)lA0 = va0;
        *(bf16x8*)lA1 = va1;
        *(bf16x8*)lB0 = vb0;
        *(bf16x8*)lB1 = vb1;
        __syncthreads();
        bf16x8 af[4], bfr[4];
#pragma unroll
        for (int i = 0; i < 4; ++i) af[i]  = *(const bf16x8*)pA[i];
#pragma unroll
        for (int i = 0; i < 4; ++i) bfr[i] = *(const bf16x8*)pB[i];
#pragma unroll
        for (int i = 0; i < 4; ++i)
#pragma unroll
            for (int j = 0; j < 4; ++j)
                acc[i][j] = __builtin_amdgcn_mfma_f32_16x16x32_bf16(af[i], bfr[j], acc[i][j], 0, 0, 0);
        __syncthreads();
    }

    // Epilogue: C/D layout col=lane&15, row=lq*4+r. col = 4*h_local + gate.
#pragma unroll
    for (int p = 0; p < 2; ++p) {
        if (wm == p) {
#pragma unroll
            for (int i = 0; i < 4; ++i)
#pragma unroll
                for (int j = 0; j < 4; ++j) {
                    int rr = i * 16 + lq * 4;
                    int cc = wn * 64 + j * 16 + lr;
#pragma unroll
                    for (int r = 0; r < 4; ++r)
                        sm.c[(rr + r) * 132 + cc] = acc[i][j][r];
                }
        }
        __syncthreads();
#pragma unroll
        for (int it = 0; it < 8; ++it) {
            int idx = it * 256 + tid;
            int r  = idx >> 5;
            int hh = idx & 31;
            size_t grow = m0 + (size_t)p * 64 + r;
            if (grow < NN) {
                float4 gv = *(const float4*)&sm.c[r * 132 + (hh << 2)];
                float4 bb = *(const float4*)&bias[n0 + (hh << 2)];
                float iv = sigf(gv.x + bb.x);
                float fv = sigf(gv.y + bb.y);
                float gg = tanhf_(gv.z + bb.z);
                float ov = sigf(gv.w + bb.w);
                int hg = (n0 >> 2) + hh;
                float cp = c_prev[grow * 128 + hg];
                float ct = fv * cp + iv * gg;
                float ht = ov * tanhf_(ct);
                out[grow * 128 + hg] = ht;
                out[(size_t)NN * 128 + grow * 128 + hg] = ct;
            }
        }
        __syncthreads();
    }
}

extern "C" void kernel_launch(void* const* d_in, const int* in_sizes, int n_in,
                              void* d_out, int out_size, void* d_ws, size_t ws_size,
                              hipStream_t stream) {
    const float* x      = (const float*)d_in[0];
    const int*   ei     = (const int*)  d_in[1];
    const float* ew     = (const float*)d_in[2];
    const float* h_prev = (const float*)d_in[3];
    const float* c_prev = (const float*)d_in[4];
    const float* Wx0    = (const float*)d_in[5];
    const float* Wx1    = (const float*)d_in[6];
    const float* Wh0    = (const float*)d_in[7];
    const float* Wh1    = (const float*)d_in[8];
    const float* bx     = (const float*)d_in[9];
    const float* bh     = (const float*)d_in[10];
    float* out = (float*)d_out;

    char* ws = (char*)d_ws;
    float*          deg    = (float*)(ws + OFF_DEG);
    int*            cnt    = (int*)  (ws + OFF_CNT);
    int*            cursor = (int*)  (ws + OFF_CUR);
    int*            rowptr = (int*)  (ws + OFF_ROWPTR);
    int*            csr_s  = (int*)  (ws + OFF_CSRS);
    float*          csr_n  = (float*)(ws + OFF_CSRN);
    unsigned short* F      = (unsigned short*)(ws + OFF_F);
    unsigned short* Wt     = (unsigned short*)(ws + OFF_WT);
    float*          bias   = (float*)(ws + OFF_BIAS);

    const int* src = ei;
    const int* dst = ei + NE;

    // zero deg+cnt+cursor (contiguous, 1,201,152 bytes = 75,072 float4)
    zero_kernel<<<(75072 + 255) / 256, 256, 0, stream>>>((float4*)ws, 75072);

    deg_kernel <<<NE / 256, 256, 0, stream>>>(src, ew, deg);
    hist_kernel<<<NE / 256, 256, 0, stream>>>(dst, cnt);
    scan_kernel<<<1, 1024, 0, stream>>>(cnt, rowptr);
    fill_kernel<<<NE / 256, 256, 0, stream>>>(src, dst, ew, deg, rowptr, cursor, csr_s, csr_n);

    gather_pack_kernel<<<MPAD / 4, 256, 0, stream>>>(rowptr, csr_s, csr_n, x, h_prev, F);
    pack_w_kernel<<<512 * 512 / 256, 256, 0, stream>>>(Wx0, Wx1, Wh0, Wh1, bx, bh, Wt, bias);

    gemm_lstm_kernel<<<dim3(4, MPAD / 128), 256, 0, stream>>>(F, Wt, bias, c_prev, out);
}

// Round 3
// 880.759 us; speedup vs baseline: 6.5811x; 1.1164x over previous
//
#include <hip/hip_runtime.h>
#include <hip/hip_bf16.h>

// Problem constants (fixed by the reference)
#define NN   100000      // nodes
#define NE   1600000     // edges
#define MPAD 100096      // 782 * 128  (padded rows for 128-row GEMM tiles)
#define KD   512         // K = CIN + CIN + H + H
// Output: h_t (NN*128) then c_t (NN*128), fp32.

typedef __attribute__((ext_vector_type(8))) short bf16x8;
typedef __attribute__((ext_vector_type(4))) float f32x4;

// ---- workspace layout (bytes) ----
#define OFF_DEG    0ull            // NN f32 (pad to 400,384)
#define OFF_CNT    400384ull       // NN i32
#define OFF_CUR    800768ull       // NN i32
#define OFF_ROWPTR 1201152ull      // (NN+1) i32 (pad to 400,512)
#define OFF_CSR    1601664ull      // NE uint2 {src, norm bits} (12,800,000)
#define OFF_XH     14401664ull     // NN*256 bf16 interleaved x|h (51,200,000)
#define OFF_F      65601664ull     // MPAD*512 bf16 (102,498,304)
#define OFF_WT     168099968ull    // 512*512 bf16
#define OFF_BIAS   168624256ull    // 512 f32
// total ~168.6 MB

__device__ __forceinline__ unsigned short f2bf(float f) {
    unsigned int u = __float_as_uint(f);
    u += 0x7fffu + ((u >> 16) & 1u);
    return (unsigned short)(u >> 16);
}
__device__ __forceinline__ float bf2f(unsigned short u) {
    return __uint_as_float(((unsigned int)u) << 16);
}
__device__ __forceinline__ float sigf(float x)  { return 1.f / (1.f + __expf(-x)); }
__device__ __forceinline__ float tanhf_(float x){ return 1.f - 2.f / (__expf(2.f * x) + 1.f); }

typedef __attribute__((address_space(3))) void lds_void;
typedef __attribute__((address_space(1))) void g_void;
__device__ __forceinline__ void gload16(const void* g, void* l) {
    __builtin_amdgcn_global_load_lds((const g_void*)g, (lds_void*)l, 16, 0, 0);
}

__global__ void zero_kernel(float4* __restrict__ p, int n4) {
    int t = blockIdx.x * 256 + threadIdx.x;
    if (t < n4) p[t] = make_float4(0.f, 0.f, 0.f, 0.f);
}

// One edge pass: weighted out-degree (by src) + dst histogram.
__global__ void deg_hist_kernel(const int* __restrict__ src, const int* __restrict__ dst,
                                const float* __restrict__ w,
                                float* __restrict__ deg, int* __restrict__ cnt) {
    int e = blockIdx.x * 256 + threadIdx.x;
    if (e >= NE) return;
    atomicAdd(&deg[src[e]], w[e]);
    atomicAdd(&cnt[dst[e]], 1);
}

// Single-block scan over 100K counters.
__global__ void scan_kernel(const int* __restrict__ cnt, int* __restrict__ rowptr) {
    __shared__ int sums[1024];
    const int T = 1024;
    const int chunk = (NN + T - 1) / T;            // 98
    int t = threadIdx.x;
    int lo = t * chunk;
    int hi = lo + chunk; if (hi > NN) hi = NN;
    int s = 0;
    for (int i = lo; i < hi; ++i) s += cnt[i];
    sums[t] = s;
    __syncthreads();
    for (int off = 1; off < T; off <<= 1) {
        int v = (t >= off) ? sums[t - off] : 0;
        __syncthreads();
        sums[t] += v;
        __syncthreads();
    }
    int base = (t == 0) ? 0 : sums[t - 1];
    for (int i = lo; i < hi; ++i) { rowptr[i] = base; base += cnt[i]; }
    if (t == T - 1) rowptr[NN] = sums[T - 1];
}

// CSR fill: norm inline; one 8B store per edge {src, norm}.
__global__ void fill_kernel(const int* __restrict__ src, const int* __restrict__ dst,
                            const float* __restrict__ w, const float* __restrict__ deg,
                            const int* __restrict__ rowptr, int* __restrict__ cursor,
                            uint2* __restrict__ csr) {
    int e = blockIdx.x * 256 + threadIdx.x;
    if (e >= NE) return;
    int s = src[e], d = dst[e];
    float ds = deg[s], dd = deg[d];
    float a = ds > 0.f ? rsqrtf(ds) : 0.f;
    float b = dd > 0.f ? rsqrtf(dd) : 0.f;
    int pos = rowptr[d] + atomicAdd(&cursor[d], 1);
    uint2 v; v.x = (unsigned)s; v.y = __float_as_uint(-(a * w[e] * b));
    csr[pos] = v;
}

// Interleaved bf16 features: XH[n][c] = bf16(x[n][c]) for c<128, bf16(h[n][c-128]) else.
__global__ void cvt_kernel(const float* __restrict__ x, const float* __restrict__ hp,
                           unsigned short* __restrict__ XH) {
    int t = blockIdx.x * 256 + threadIdx.x;      // 0 .. NN*64-1
    int n = t >> 6, q = t & 63;
    const float* s = (q < 32) ? (x + (size_t)n * 128 + (q << 2))
                              : (hp + (size_t)n * 128 + ((q - 32) << 2));
    float4 v = *(const float4*)s;
    *(ushort4*)(XH + (size_t)n * 256 + (q << 2)) =
        make_ushort4(f2bf(v.x), f2bf(v.y), f2bf(v.z), f2bf(v.w));
}

// One wave per node; lane owns 4 of the 256 XH columns (8B/lane gather).
// Register accumulate (no atomics), write F row directly in bf16.
__launch_bounds__(256)
__global__ void gather_pack_kernel(const int* __restrict__ rowptr,
                                   const uint2* __restrict__ csr,
                                   const unsigned short* __restrict__ XH,
                                   unsigned short* __restrict__ F) {
    int node = (blockIdx.x * 256 + threadIdx.x) >> 6;
    int lane = threadIdx.x & 63;
    if (node >= MPAD) return;
    const int c4 = lane << 2;                    // XH column 0..252
    const int selfOff = (lane < 32) ? c4 : c4 + 128;  // F col for self term
    unsigned short* Frow = F + (size_t)node * KD;
    if (node >= NN) {                            // pad rows -> zeros
        *(ushort4*)(Frow + selfOff)       = make_ushort4(0, 0, 0, 0);
        *(ushort4*)(Frow + selfOff + 128) = make_ushort4(0, 0, 0, 0);
        return;
    }
    int lo = rowptr[node], hi = rowptr[node + 1];
    float4 acc = make_float4(0.f, 0.f, 0.f, 0.f);
    int e = lo;
    for (; e + 1 < hi; e += 2) {
        uint2 e0 = csr[e], e1 = csr[e + 1];
        ushort4 v0 = *(const ushort4*)(XH + (size_t)e0.x * 256 + c4);
        ushort4 v1 = *(const ushort4*)(XH + (size_t)e1.x * 256 + c4);
        float n0 = __uint_as_float(e0.y), n1 = __uint_as_float(e1.y);
        acc.x += n0 * bf2f(v0.x); acc.y += n0 * bf2f(v0.y);
        acc.z += n0 * bf2f(v0.z); acc.w += n0 * bf2f(v0.w);
        acc.x += n1 * bf2f(v1.x); acc.y += n1 * bf2f(v1.y);
        acc.z += n1 * bf2f(v1.z); acc.w += n1 * bf2f(v1.w);
    }
    if (e < hi) {
        uint2 e0 = csr[e];
        ushort4 v0 = *(const ushort4*)(XH + (size_t)e0.x * 256 + c4);
        float n0 = __uint_as_float(e0.y);
        acc.x += n0 * bf2f(v0.x); acc.y += n0 * bf2f(v0.y);
        acc.z += n0 * bf2f(v0.z); acc.w += n0 * bf2f(v0.w);
    }
    ushort4 self = *(const ushort4*)(XH + (size_t)node * 256 + c4);
    *(ushort4*)(Frow + selfOff) = self;
    *(ushort4*)(Frow + selfOff + 128) =
        make_ushort4(f2bf(acc.x), f2bf(acc.y), f2bf(acc.z), f2bf(acc.w));
}

// Wt[col][k] (B^T), col = 4*h + g (gate-interleaved).
__global__ void pack_w_kernel(const float* __restrict__ Wx0, const float* __restrict__ Wx1,
                              const float* __restrict__ Wh0, const float* __restrict__ Wh1,
                              const float* __restrict__ bx,  const float* __restrict__ bh,
                              unsigned short* __restrict__ Wt, float* __restrict__ bias) {
    int t = blockIdx.x * 256 + threadIdx.x;   // 0 .. 512*512-1
    int col = t >> 9, k = t & 511;
    int h = col >> 2, g = col & 3;
    const float* W; int kk;
    if      (k < 128) { W = Wx0; kk = k; }
    else if (k < 256) { W = Wx1; kk = k - 128; }
    else if (k < 384) { W = Wh0; kk = k - 256; }
    else              { W = Wh1; kk = k - 384; }
    float v = W[((size_t)(g << 7) + kk) * 128 + h];
    Wt[(size_t)col * KD + k] = f2bf(v);
    if (k == 0) bias[col] = bx[(g << 7) + h] + bh[(g << 7) + h];
}

// GEMM 128x128 tile/block, global_load_lds width-16 staging (m97 structure),
// 4 waves 2x2, each wave 4x4 of 16x16x32 bf16 MFMA. Fused LSTM epilogue.
__launch_bounds__(256)
__global__ void gemm_lstm_kernel(const unsigned short* __restrict__ F,
                                 const unsigned short* __restrict__ Wt,
                                 const float* __restrict__ bias,
                                 const float* __restrict__ c_prev,
                                 float* __restrict__ out) {
    __shared__ __align__(16) union {
        struct { short a[128 * 32]; short b[128 * 32]; } t;   // K-loop tiles (16 KB)
        float c[64 * 132];                                    // epilogue buf (33 KB)
    } sm;

    const int tid  = threadIdx.x;
    const int lane = tid & 63;
    const int wave = tid >> 6;
    const int wm = wave >> 1, wn = wave & 1;
    const int lr = lane & 15, lq = lane >> 4;

    const int ntile = blockIdx.x;             // 0..3
    const int mtile = blockIdx.y;             // 0..781
    const size_t m0 = (size_t)mtile * 128;
    const int n0 = ntile * 128;

    // staging: lane l of wave w covers A-row w*16 + (l>>2), 16B chunk (l&3)
    const int arow = tid >> 2;                // 0..63
    const int ak   = (tid & 3) << 3;          // elem offset 0,8,16,24
    const short* gA0 = (const short*)F  + (m0 + arow) * KD + ak;
    const short* gA1 = gA0 + (size_t)64 * KD;
    const short* gB0 = (const short*)Wt + (size_t)(n0 + arow) * KD + ak;
    const short* gB1 = gB0 + (size_t)64 * KD;
    // wave-uniform LDS bases: lane l lands at base + 16*l
    short* lA0 = &sm.t.a[(wave * 16) * 32];
    short* lA1 = &sm.t.a[(64 + wave * 16) * 32];
    short* lB0 = &sm.t.b[(wave * 16) * 32];
    short* lB1 = &sm.t.b[(64 + wave * 16) * 32];

    const short* pA[4]; const short* pB[4];
#pragma unroll
    for (int i = 0; i < 4; ++i) {
        pA[i] = &sm.t.a[(wm * 64 + i * 16 + lr) * 32 + lq * 8];
        pB[i] = &sm.t.b[(wn * 64 + i * 16 + lr) * 32 + lq * 8];
    }

    f32x4 acc[4][4];
#pragma unroll
    for (int i = 0; i < 4; ++i)
#pragma unroll
        for (int j = 0; j < 4; ++j) acc[i][j] = (f32x4){0.f, 0.f, 0.f, 0.f};

    for (int kt = 0; kt < KD / 32; ++kt) {
        const int ko = kt * 32;
        gload16(gA0 + ko, lA0);
        gload16(gA1 + ko, lA1);
        gload16(gB0 + ko, lB0);
        gload16(gB1 + ko, lB1);
        __syncthreads();
        bf16x8 af[4], bfr[4];
#pragma unroll
        for (int i = 0; i < 4; ++i) af[i]  = *(const bf16x8*)pA[i];
#pragma unroll
        for (int i = 0; i < 4; ++i) bfr[i] = *(const bf16x8*)pB[i];
#pragma unroll
        for (int i = 0; i < 4; ++i)
#pragma unroll
            for (int j = 0; j < 4; ++j)
                acc[i][j] = __builtin_amdgcn_mfma_f32_16x16x32_bf16(af[i], bfr[j], acc[i][j], 0, 0, 0);
        __syncthreads();
    }

    // Epilogue: C/D layout col=lane&15, row=lq*4+r. col = 4*h_local + gate.
#pragma unroll
    for (int p = 0; p < 2; ++p) {
        if (wm == p) {
#pragma unroll
            for (int i = 0; i < 4; ++i)
#pragma unroll
                for (int j = 0; j < 4; ++j) {
                    int rr = i * 16 + lq * 4;
                    int cc = wn * 64 + j * 16 + lr;
#pragma unroll
                    for (int r = 0; r < 4; ++r)
                        sm.c[(rr + r) * 132 + cc] = acc[i][j][r];
                }
        }
        __syncthreads();
#pragma unroll
        for (int it = 0; it < 8; ++it) {
            int idx = it * 256 + tid;
            int r  = idx >> 5;
            int hh = idx & 31;
            size_t grow = m0 + (size_t)p * 64 + r;
            if (grow < NN) {
                float4 gv = *(const float4*)&sm.c[r * 132 + (hh << 2)];
                float4 bb = *(const float4*)&bias[n0 + (hh << 2)];
                float iv = sigf(gv.x + bb.x);
                float fv = sigf(gv.y + bb.y);
                float gg = tanhf_(gv.z + bb.z);
                float ov = sigf(gv.w + bb.w);
                int hg = (n0 >> 2) + hh;
                float cp = c_prev[grow * 128 + hg];
                float ct = fv * cp + iv * gg;
                float ht = ov * tanhf_(ct);
                out[grow * 128 + hg] = ht;
                out[(size_t)NN * 128 + grow * 128 + hg] = ct;
            }
        }
        __syncthreads();
    }
}

extern "C" void kernel_launch(void* const* d_in, const int* in_sizes, int n_in,
                              void* d_out, int out_size, void* d_ws, size_t ws_size,
                              hipStream_t stream) {
    const float* x      = (const float*)d_in[0];
    const int*   ei     = (const int*)  d_in[1];
    const float* ew     = (const float*)d_in[2];
    const float* h_prev = (const float*)d_in[3];
    const float* c_prev = (const float*)d_in[4];
    const float* Wx0    = (const float*)d_in[5];
    const float* Wx1    = (const float*)d_in[6];
    const float* Wh0    = (const float*)d_in[7];
    const float* Wh1    = (const float*)d_in[8];
    const float* bx     = (const float*)d_in[9];
    const float* bh     = (const float*)d_in[10];
    float* out = (float*)d_out;

    char* ws = (char*)d_ws;
    float*          deg    = (float*)(ws + OFF_DEG);
    int*            cnt    = (int*)  (ws + OFF_CNT);
    int*            cursor = (int*)  (ws + OFF_CUR);
    int*            rowptr = (int*)  (ws + OFF_ROWPTR);
    uint2*          csr    = (uint2*)(ws + OFF_CSR);
    unsigned short* XH     = (unsigned short*)(ws + OFF_XH);
    unsigned short* F      = (unsigned short*)(ws + OFF_F);
    unsigned short* Wt     = (unsigned short*)(ws + OFF_WT);
    float*          bias   = (float*)(ws + OFF_BIAS);

    const int* src = ei;
    const int* dst = ei + NE;

    // zero deg+cnt+cursor (contiguous, 1,201,152 B = 75,072 float4)
    zero_kernel<<<(75072 + 255) / 256, 256, 0, stream>>>((float4*)ws, 75072);

    deg_hist_kernel<<<NE / 256, 256, 0, stream>>>(src, dst, ew, deg, cnt);
    scan_kernel<<<1, 1024, 0, stream>>>(cnt, rowptr);
    fill_kernel<<<NE / 256, 256, 0, stream>>>(src, dst, ew, deg, rowptr, cursor, csr);

    cvt_kernel<<<NN * 64 / 256, 256, 0, stream>>>(x, h_prev, XH);
    gather_pack_kernel<<<MPAD / 4, 256, 0, stream>>>(rowptr, csr, XH, F);
    pack_w_kernel<<<512 * 512 / 256, 256, 0, stream>>>(Wx0, Wx1, Wh0, Wh1, bx, bh, Wt, bias);

    gemm_lstm_kernel<<<dim3(4, MPAD / 128), 256, 0, stream>>>(F, Wt, bias, c_prev, out);
}

// Round 4
// 797.659 us; speedup vs baseline: 7.2668x; 1.1042x over previous
//
#include <hip/hip_runtime.h>
#include <hip/hip_bf16.h>

// Problem constants (fixed by the reference)
#define NN   100000      // nodes
#define NE   1600000     // edges
#define MPAD 100096      // 782 * 128  (padded rows for 128-row GEMM tiles)
#define KD   512         // K = CIN + CIN + H + H
// Output: h_t (NN*128) then c_t (NN*128), fp32.

typedef __attribute__((ext_vector_type(8))) short bf16x8;
typedef __attribute__((ext_vector_type(4))) float f32x4;

// ---- workspace layout (bytes) ----
#define OFF_DEG    0ull            // NN f32 (pad to 400,384)
#define OFF_CNT    400384ull       // NN i32
#define OFF_CUR    800768ull       // NN i32
#define OFF_ROWPTR 1201152ull      // (NN+1) i32 (pad to 400,512)
#define OFF_CSR    1601664ull      // NE uint2 {src, norm bits} (12,800,000)
#define OFF_XH     14401664ull     // NN*256 bf16 interleaved x|h (51,200,000)
#define OFF_F      65601664ull     // MPAD*512 bf16 (102,498,304)
#define OFF_WT     168099968ull    // 512*512 bf16
#define OFF_BIAS   168624256ull    // 512 f32
// total ~168.6 MB

__device__ __forceinline__ unsigned short f2bf(float f) {
    unsigned int u = __float_as_uint(f);
    u += 0x7fffu + ((u >> 16) & 1u);
    return (unsigned short)(u >> 16);
}
__device__ __forceinline__ float bf2f(unsigned short u) {
    return __uint_as_float(((unsigned int)u) << 16);
}
__device__ __forceinline__ float sigf(float x)  { return 1.f / (1.f + __expf(-x)); }
__device__ __forceinline__ float tanhf_(float x){ return 1.f - 2.f / (__expf(2.f * x) + 1.f); }

typedef __attribute__((address_space(3))) void lds_void;
typedef __attribute__((address_space(1))) void g_void;
__device__ __forceinline__ void gload16(const void* g, void* l) {
    __builtin_amdgcn_global_load_lds((const g_void*)g, (lds_void*)l, 16, 0, 0);
}

__global__ void zero_kernel(float4* __restrict__ p, int n4) {
    int t = blockIdx.x * 256 + threadIdx.x;
    if (t < n4) p[t] = make_float4(0.f, 0.f, 0.f, 0.f);
}

// One edge pass: weighted out-degree (by src) + dst histogram.
__global__ void deg_hist_kernel(const int* __restrict__ src, const int* __restrict__ dst,
                                const float* __restrict__ w,
                                float* __restrict__ deg, int* __restrict__ cnt) {
    int e = blockIdx.x * 256 + threadIdx.x;
    if (e >= NE) return;
    atomicAdd(&deg[src[e]], w[e]);
    atomicAdd(&cnt[dst[e]], 1);
}

// Coalesced single-block exclusive scan: 98 rounds of 1024-wide loads,
// wave shfl-scan + cross-wave LDS scan per round.
__global__ void scan_kernel(const int* __restrict__ cnt, int* __restrict__ rowptr) {
    __shared__ int wsum[16];
    int t = threadIdx.x, lane = t & 63, w = t >> 6;
    int base = 0;
    for (int r0 = 0; r0 < NN; r0 += 1024) {
        int i = r0 + t;
        int v = (i < NN) ? cnt[i] : 0;
        int s = v;
#pragma unroll
        for (int off = 1; off < 64; off <<= 1) {
            int u = __shfl_up(s, off, 64);
            if (lane >= off) s += u;
        }
        if (lane == 63) wsum[w] = s;
        __syncthreads();
        if (w == 0) {
            int ws = (lane < 16) ? wsum[lane] : 0;
#pragma unroll
            for (int off = 1; off < 16; off <<= 1) {
                int u = __shfl_up(ws, off, 64);
                if (lane >= off) ws += u;
            }
            if (lane < 16) wsum[lane] = ws;
        }
        __syncthreads();
        int wbase = (w == 0) ? 0 : wsum[w - 1];
        if (i < NN) rowptr[i] = base + wbase + s - v;   // exclusive
        base += wsum[15];
        __syncthreads();                                 // wsum reused next round
    }
    if (t == 0) rowptr[NN] = base;
}

// CSR fill: norm inline; one 8B store per edge {src, norm}.
__global__ void fill_kernel(const int* __restrict__ src, const int* __restrict__ dst,
                            const float* __restrict__ w, const float* __restrict__ deg,
                            const int* __restrict__ rowptr, int* __restrict__ cursor,
                            uint2* __restrict__ csr) {
    int e = blockIdx.x * 256 + threadIdx.x;
    if (e >= NE) return;
    int s = src[e], d = dst[e];
    float ds = deg[s], dd = deg[d];
    float a = ds > 0.f ? rsqrtf(ds) : 0.f;
    float b = dd > 0.f ? rsqrtf(dd) : 0.f;
    int pos = rowptr[d] + atomicAdd(&cursor[d], 1);
    uint2 v; v.x = (unsigned)s; v.y = __float_as_uint(-(a * w[e] * b));
    csr[pos] = v;
}

// Interleaved bf16 features: XH[n][c] = bf16(x[n][c]) for c<128, bf16(h[n][c-128]) else.
__global__ void cvt_kernel(const float* __restrict__ x, const float* __restrict__ hp,
                           unsigned short* __restrict__ XH) {
    int t = blockIdx.x * 256 + threadIdx.x;      // 0 .. NN*64-1
    int n = t >> 6, q = t & 63;
    const float* s = (q < 32) ? (x + (size_t)n * 128 + (q << 2))
                              : (hp + (size_t)n * 128 + ((q - 32) << 2));
    float4 v = *(const float4*)s;
    *(ushort4*)(XH + (size_t)n * 256 + (q << 2)) =
        make_ushort4(f2bf(v.x), f2bf(v.y), f2bf(v.z), f2bf(v.w));
}

// One wave per node; lane owns 4 of the 256 XH columns (8B/lane gather).
__launch_bounds__(256)
__global__ void gather_pack_kernel(const int* __restrict__ rowptr,
                                   const uint2* __restrict__ csr,
                                   const unsigned short* __restrict__ XH,
                                   unsigned short* __restrict__ F) {
    int node = (blockIdx.x * 256 + threadIdx.x) >> 6;
    int lane = threadIdx.x & 63;
    if (node >= MPAD) return;
    const int c4 = lane << 2;                    // XH column 0..252
    const int selfOff = (lane < 32) ? c4 : c4 + 128;  // F col for self term
    unsigned short* Frow = F + (size_t)node * KD;
    if (node >= NN) {                            // pad rows -> zeros
        *(ushort4*)(Frow + selfOff)       = make_ushort4(0, 0, 0, 0);
        *(ushort4*)(Frow + selfOff + 128) = make_ushort4(0, 0, 0, 0);
        return;
    }
    int lo = rowptr[node], hi = rowptr[node + 1];
    float4 acc = make_float4(0.f, 0.f, 0.f, 0.f);
    int e = lo;
    for (; e + 1 < hi; e += 2) {
        uint2 e0 = csr[e], e1 = csr[e + 1];
        ushort4 v0 = *(const ushort4*)(XH + (size_t)e0.x * 256 + c4);
        ushort4 v1 = *(const ushort4*)(XH + (size_t)e1.x * 256 + c4);
        float n0 = __uint_as_float(e0.y), n1 = __uint_as_float(e1.y);
        acc.x += n0 * bf2f(v0.x); acc.y += n0 * bf2f(v0.y);
        acc.z += n0 * bf2f(v0.z); acc.w += n0 * bf2f(v0.w);
        acc.x += n1 * bf2f(v1.x); acc.y += n1 * bf2f(v1.y);
        acc.z += n1 * bf2f(v1.z); acc.w += n1 * bf2f(v1.w);
    }
    if (e < hi) {
        uint2 e0 = csr[e];
        ushort4 v0 = *(const ushort4*)(XH + (size_t)e0.x * 256 + c4);
        float n0 = __uint_as_float(e0.y);
        acc.x += n0 * bf2f(v0.x); acc.y += n0 * bf2f(v0.y);
        acc.z += n0 * bf2f(v0.z); acc.w += n0 * bf2f(v0.w);
    }
    ushort4 self = *(const ushort4*)(XH + (size_t)node * 256 + c4);
    *(ushort4*)(Frow + selfOff) = self;
    *(ushort4*)(Frow + selfOff + 128) =
        make_ushort4(f2bf(acc.x), f2bf(acc.y), f2bf(acc.z), f2bf(acc.w));
}

// Wt[col][k] (B^T), col = 4*h + g (gate-interleaved).
__global__ void pack_w_kernel(const float* __restrict__ Wx0, const float* __restrict__ Wx1,
                              const float* __restrict__ Wh0, const float* __restrict__ Wh1,
                              const float* __restrict__ bx,  const float* __restrict__ bh,
                              unsigned short* __restrict__ Wt, float* __restrict__ bias) {
    int t = blockIdx.x * 256 + threadIdx.x;   // 0 .. 512*512-1
    int col = t >> 9, k = t & 511;
    int h = col >> 2, g = col & 3;
    const float* W; int kk;
    if      (k < 128) { W = Wx0; kk = k; }
    else if (k < 256) { W = Wx1; kk = k - 128; }
    else if (k < 384) { W = Wh0; kk = k - 256; }
    else              { W = Wh1; kk = k - 384; }
    float v = W[((size_t)(g << 7) + kk) * 128 + h];
    Wt[(size_t)col * KD + k] = f2bf(v);
    if (k == 0) bias[col] = bx[(g << 7) + h] + bh[(g << 7) + h];
}

// GEMM 128x128 tile/block: double-buffered global_load_lds staging, XOR bank
// swizzle, XCD-co-scheduled grid, 16-row-phase fused LSTM epilogue.
__launch_bounds__(256)
__global__ void gemm_lstm_kernel(const unsigned short* __restrict__ F,
                                 const unsigned short* __restrict__ Wt,
                                 const float* __restrict__ bias,
                                 const float* __restrict__ c_prev,
                                 float* __restrict__ out) {
    __shared__ __align__(16) union {
        struct { short a[2][128 * 32]; short b[2][128 * 32]; } t;  // 32 KB dbuf tiles
        float c[16 * 132];                                         // 8.4 KB epilogue
    } sm;

    const int tid  = threadIdx.x;
    const int lane = tid & 63;
    const int wave = tid >> 6;
    const int wm = wave >> 1, wn = wave & 1;
    const int lr = lane & 15, lq = lane >> 4;

    // XCD co-schedule: blocks {k,k+8,k+16,k+24} share mtile -> same XCD L2.
    const int b = blockIdx.x;                 // 0..3135
    const int ntile = (b >> 3) & 3;
    const int mtile = (b & 7) | ((b >> 5) << 3);
    if (mtile >= 782) return;
    const size_t m0 = (size_t)mtile * 128;
    const int n0 = ntile * 128;

    // staging: thread t covers row t>>2 (+0/64), global chunk (t&3)^(row&3)
    const int arow = tid >> 2;                // 0..63
    const int ak   = (((tid & 3) ^ (arow & 3)) << 3);   // XOR-swizzled chunk
    const short* gA0 = (const short*)F  + (m0 + arow) * KD + ak;
    const short* gA1 = gA0 + (size_t)64 * KD;
    const short* gB0 = (const short*)Wt + (size_t)(n0 + arow) * KD + ak;
    const short* gB1 = gB0 + (size_t)64 * KD;

    // fragment LDS offsets (shorts): chunk lq of row r lives at slot lq^(r&3)
    int offA[4], offB[4];
#pragma unroll
    for (int i = 0; i < 4; ++i) {
        offA[i] = (wm * 64 + i * 16 + lr) * 32 + ((lq ^ (lr & 3)) << 3);
        offB[i] = (wn * 64 + i * 16 + lr) * 32 + ((lq ^ (lr & 3)) << 3);
    }

    f32x4 acc[4][4];
#pragma unroll
    for (int i = 0; i < 4; ++i)
#pragma unroll
        for (int j = 0; j < 4; ++j) acc[i][j] = (f32x4){0.f, 0.f, 0.f, 0.f};

    auto stage = [&](int kt, int buf) {
        const int ko = kt * 32;
        gload16(gA0 + ko, &sm.t.a[buf][wave * 512]);
        gload16(gA1 + ko, &sm.t.a[buf][2048 + wave * 512]);
        gload16(gB0 + ko, &sm.t.b[buf][wave * 512]);
        gload16(gB1 + ko, &sm.t.b[buf][2048 + wave * 512]);
    };

    stage(0, 0);
    for (int kt = 0; kt < KD / 32; ++kt) {
        __syncthreads();                       // staging of buf (kt&1) complete
        if (kt + 1 < KD / 32) stage(kt + 1, (kt + 1) & 1);   // async prefetch
        const int buf = kt & 1;
        bf16x8 af[4], bfr[4];
#pragma unroll
        for (int i = 0; i < 4; ++i) af[i]  = *(const bf16x8*)&sm.t.a[buf][offA[i]];
#pragma unroll
        for (int i = 0; i < 4; ++i) bfr[i] = *(const bf16x8*)&sm.t.b[buf][offB[i]];
#pragma unroll
        for (int i = 0; i < 4; ++i)
#pragma unroll
            for (int j = 0; j < 4; ++j)
                acc[i][j] = __builtin_amdgcn_mfma_f32_16x16x32_bf16(af[i], bfr[j], acc[i][j], 0, 0, 0);
    }
    __syncthreads();                           // drain last ds_reads before c overlay

    // Epilogue: 8 phases of 16 rows. C/D layout col=lane&15, row=lq*4+r.
    for (int p = 0; p < 8; ++p) {
        const int pm = p >> 2, pi = p & 3;
        if (wm == pm) {
#pragma unroll
            for (int j = 0; j < 4; ++j)
#pragma unroll
                for (int r = 0; r < 4; ++r)
                    sm.c[(lq * 4 + r) * 132 + wn * 64 + j * 16 + lr] = acc[pi][j][r];
        }
        __syncthreads();
#pragma unroll
        for (int it = 0; it < 2; ++it) {
            int idx = it * 256 + tid;
            int r = idx >> 5, hh = idx & 31;
            size_t grow = m0 + p * 16 + r;
            if (grow < NN) {
                float4 gv = *(const float4*)&sm.c[r * 132 + (hh << 2)];
                float4 bb = *(const float4*)&bias[n0 + (hh << 2)];
                float iv = sigf(gv.x + bb.x);
                float fv = sigf(gv.y + bb.y);
                float gg = tanhf_(gv.z + bb.z);
                float ov = sigf(gv.w + bb.w);
                int hg = (n0 >> 2) + hh;
                float cp = c_prev[grow * 128 + hg];
                float ct = fv * cp + iv * gg;
                float ht = ov * tanhf_(ct);
                out[grow * 128 + hg] = ht;
                out[(size_t)NN * 128 + grow * 128 + hg] = ct;
            }
        }
        __syncthreads();
    }
}

extern "C" void kernel_launch(void* const* d_in, const int* in_sizes, int n_in,
                              void* d_out, int out_size, void* d_ws, size_t ws_size,
                              hipStream_t stream) {
    const float* x      = (const float*)d_in[0];
    const int*   ei     = (const int*)  d_in[1];
    const float* ew     = (const float*)d_in[2];
    const float* h_prev = (const float*)d_in[3];
    const float* c_prev = (const float*)d_in[4];
    const float* Wx0    = (const float*)d_in[5];
    const float* Wx1    = (const float*)d_in[6];
    const float* Wh0    = (const float*)d_in[7];
    const float* Wh1    = (const float*)d_in[8];
    const float* bx     = (const float*)d_in[9];
    const float* bh     = (const float*)d_in[10];
    float* out = (float*)d_out;

    char* ws = (char*)d_ws;
    float*          deg    = (float*)(ws + OFF_DEG);
    int*            cnt    = (int*)  (ws + OFF_CNT);
    int*            cursor = (int*)  (ws + OFF_CUR);
    int*            rowptr = (int*)  (ws + OFF_ROWPTR);
    uint2*          csr    = (uint2*)(ws + OFF_CSR);
    unsigned short* XH     = (unsigned short*)(ws + OFF_XH);
    unsigned short* F      = (unsigned short*)(ws + OFF_F);
    unsigned short* Wt     = (unsigned short*)(ws + OFF_WT);
    float*          bias   = (float*)(ws + OFF_BIAS);

    const int* src = ei;
    const int* dst = ei + NE;

    // zero deg+cnt+cursor (contiguous, 1,201,152 B = 75,072 float4)
    zero_kernel<<<(75072 + 255) / 256, 256, 0, stream>>>((float4*)ws, 75072);

    deg_hist_kernel<<<NE / 256, 256, 0, stream>>>(src, dst, ew, deg, cnt);
    scan_kernel<<<1, 1024, 0, stream>>>(cnt, rowptr);
    fill_kernel<<<NE / 256, 256, 0, stream>>>(src, dst, ew, deg, rowptr, cursor, csr);

    cvt_kernel<<<NN * 64 / 256, 256, 0, stream>>>(x, h_prev, XH);
    gather_pack_kernel<<<MPAD / 4, 256, 0, stream>>>(rowptr, csr, XH, F);
    pack_w_kernel<<<512 * 512 / 256, 256, 0, stream>>>(Wx0, Wx1, Wh0, Wh1, bx, bh, Wt, bias);

    gemm_lstm_kernel<<<3136, 256, 0, stream>>>(F, Wt, bias, c_prev, out);
}

// Round 5
// 700.244 us; speedup vs baseline: 8.2777x; 1.1391x over previous
//
#include <hip/hip_runtime.h>
#include <hip/hip_bf16.h>

// Problem constants (fixed by the reference)
#define NN   100000      // nodes
#define NE   1600000     // edges
#define MPAD 100096      // 782 * 128  (padded rows for 128-row GEMM tiles)
// Output: h_t (NN*128) then c_t (NN*128), fp32.

typedef __attribute__((ext_vector_type(8))) short bf16x8;
typedef __attribute__((ext_vector_type(4))) float f32x4;

// ---- workspace layout (bytes) ----
#define OFF_DEG    0ull            // NN f32 (pad 400,384); deg+cnt+cur zeroed together
#define OFF_CNT    400384ull       // NN i32
#define OFF_CUR    800768ull       // NN i32
#define OFF_ROWPTR 1201152ull      // (NN+1) i32 (pad 400,512)
#define OFF_BSUM   1601664ull      // 98 i32 (pad 512)
#define OFF_CSR    1602176ull      // NE uint2 {src, norm bits} (12,800,000)
#define OFF_XH     14402176ull     // MPAD*256 bf16 interleaved x|h (51,249,152)
#define OFF_FP     65651328ull     // MPAD*256 bf16 [Lx|Lh]      (51,249,152)
#define OFF_WT     116900480ull    // 512*512 bf16 (524,288)
#define OFF_BIAS   117424768ull    // 512 f32
// total ~117.4 MB

__device__ __forceinline__ unsigned short f2bf(float f) {
    unsigned int u = __float_as_uint(f);
    u += 0x7fffu + ((u >> 16) & 1u);
    return (unsigned short)(u >> 16);
}
__device__ __forceinline__ float bf2f(unsigned short u) {
    return __uint_as_float(((unsigned int)u) << 16);
}
__device__ __forceinline__ float sigf(float x)  { return 1.f / (1.f + __expf(-x)); }
__device__ __forceinline__ float tanhf_(float x){ return 1.f - 2.f / (__expf(2.f * x) + 1.f); }

typedef __attribute__((address_space(3))) void lds_void;
typedef __attribute__((address_space(1))) void g_void;
__device__ __forceinline__ void gload16(const void* g, void* l) {
    __builtin_amdgcn_global_load_lds((const g_void*)g, (lds_void*)l, 16, 0, 0);
}

__global__ void zero_kernel(float4* __restrict__ p, int n4) {
    int t = blockIdx.x * 256 + threadIdx.x;
    if (t < n4) p[t] = make_float4(0.f, 0.f, 0.f, 0.f);
}

// One edge pass: weighted out-degree (by src) + dst histogram.
__global__ void deg_hist_kernel(const int* __restrict__ src, const int* __restrict__ dst,
                                const float* __restrict__ w,
                                float* __restrict__ deg, int* __restrict__ cnt) {
    int e = blockIdx.x * 256 + threadIdx.x;
    if (e >= NE) return;
    atomicAdd(&deg[src[e]], w[e]);
    atomicAdd(&cnt[dst[e]], 1);
}

// ---- 3-phase parallel exclusive scan of cnt -> rowptr ----
__global__ void scan_part_kernel(const int* __restrict__ cnt, int* __restrict__ rowptr,
                                 int* __restrict__ bsum) {
    __shared__ int wsum[16];
    int t = threadIdx.x, lane = t & 63, w = t >> 6;
    int i = blockIdx.x * 1024 + t;
    int v = (i < NN) ? cnt[i] : 0;
    int s = v;
#pragma unroll
    for (int off = 1; off < 64; off <<= 1) {
        int u = __shfl_up(s, off, 64);
        if (lane >= off) s += u;
    }
    if (lane == 63) wsum[w] = s;
    __syncthreads();
    if (w == 0) {
        int ws = (lane < 16) ? wsum[lane] : 0;
#pragma unroll
        for (int off = 1; off < 16; off <<= 1) {
            int u = __shfl_up(ws, off, 64);
            if (lane >= off) ws += u;
        }
        if (lane < 16) wsum[lane] = ws;
    }
    __syncthreads();
    int wbase = (w == 0) ? 0 : wsum[w - 1];
    if (i < NN) rowptr[i] = wbase + s - v;          // block-local exclusive
    if (t == 1023) bsum[blockIdx.x] = wsum[15];
}

__global__ void scan_top_kernel(int* __restrict__ bsum, int* __restrict__ rowptr) {
    if (threadIdx.x == 0) {
        int a = 0;
        for (int b = 0; b < 98; ++b) { int t = bsum[b]; bsum[b] = a; a += t; }
        rowptr[NN] = a;
    }
}

__global__ void scan_add_kernel(const int* __restrict__ bsum, int* __restrict__ rowptr) {
    int i = blockIdx.x * 1024 + threadIdx.x;
    if (i < NN) rowptr[i] += bsum[blockIdx.x];
}

// CSR fill: norm inline; one 8B store per edge {src, norm}.
__global__ void fill_kernel(const int* __restrict__ src, const int* __restrict__ dst,
                            const float* __restrict__ w, const float* __restrict__ deg,
                            const int* __restrict__ rowptr, int* __restrict__ cursor,
                            uint2* __restrict__ csr) {
    int e = blockIdx.x * 256 + threadIdx.x;
    if (e >= NE) return;
    int s = src[e], d = dst[e];
    float ds = deg[s], dd = deg[d];
    float a = ds > 0.f ? rsqrtf(ds) : 0.f;
    float b = dd > 0.f ? rsqrtf(dd) : 0.f;
    int pos = rowptr[d] + atomicAdd(&cursor[d], 1);
    uint2 v; v.x = (unsigned)s; v.y = __float_as_uint(-(a * w[e] * b));
    csr[pos] = v;
}

// Interleaved bf16 features: XH[n] = [x(128) | h(128)]; pad rows zero.
__global__ void cvt_kernel(const float* __restrict__ x, const float* __restrict__ hp,
                           unsigned short* __restrict__ XH) {
    int t = blockIdx.x * 256 + threadIdx.x;      // 0 .. MPAD*64-1
    int n = t >> 6, q = t & 63;
    ushort4 o = make_ushort4(0, 0, 0, 0);
    if (n < NN) {
        const float* s = (q < 32) ? (x + (size_t)n * 128 + (q << 2))
                                  : (hp + (size_t)n * 128 + ((q - 32) << 2));
        float4 v = *(const float4*)s;
        o = make_ushort4(f2bf(v.x), f2bf(v.y), f2bf(v.z), f2bf(v.w));
    }
    *(ushort4*)(XH + (size_t)n * 256 + (q << 2)) = o;
}

// One wave per node; lane owns 4 of 256 XH cols (8B/lane gather); Fp = [Lx|Lh].
__launch_bounds__(256)
__global__ void gather_pack_kernel(const int* __restrict__ rowptr,
                                   const uint2* __restrict__ csr,
                                   const unsigned short* __restrict__ XH,
                                   unsigned short* __restrict__ Fp) {
    int node = (blockIdx.x * 256 + threadIdx.x) >> 6;
    int lane = threadIdx.x & 63;
    if (node >= MPAD) return;
    const int c4 = lane << 2;                    // col 0..252
    unsigned short* Frow = Fp + (size_t)node * 256;
    if (node >= NN) {                            // pad rows -> zeros
        *(ushort4*)(Frow + c4) = make_ushort4(0, 0, 0, 0);
        return;
    }
    int lo = rowptr[node], hi = rowptr[node + 1];
    float4 acc = make_float4(0.f, 0.f, 0.f, 0.f);
    int e = lo;
    for (; e + 1 < hi; e += 2) {
        uint2 e0 = csr[e], e1 = csr[e + 1];
        ushort4 v0 = *(const ushort4*)(XH + (size_t)e0.x * 256 + c4);
        ushort4 v1 = *(const ushort4*)(XH + (size_t)e1.x * 256 + c4);
        float n0 = __uint_as_float(e0.y), n1 = __uint_as_float(e1.y);
        acc.x += n0 * bf2f(v0.x); acc.y += n0 * bf2f(v0.y);
        acc.z += n0 * bf2f(v0.z); acc.w += n0 * bf2f(v0.w);
        acc.x += n1 * bf2f(v1.x); acc.y += n1 * bf2f(v1.y);
        acc.z += n1 * bf2f(v1.z); acc.w += n1 * bf2f(v1.w);
    }
    if (e < hi) {
        uint2 e0 = csr[e];
        ushort4 v0 = *(const ushort4*)(XH + (size_t)e0.x * 256 + c4);
        float n0 = __uint_as_float(e0.y);
        acc.x += n0 * bf2f(v0.x); acc.y += n0 * bf2f(v0.y);
        acc.z += n0 * bf2f(v0.z); acc.w += n0 * bf2f(v0.w);
    }
    *(ushort4*)(Frow + c4) =
        make_ushort4(f2bf(acc.x), f2bf(acc.y), f2bf(acc.z), f2bf(acc.w));
}

// Wt[col][k] (B^T), col = 4*h + g (gate-interleaved), k in [x|Lx|h|Lh] order.
__global__ void pack_w_kernel(const float* __restrict__ Wx0, const float* __restrict__ Wx1,
                              const float* __restrict__ Wh0, const float* __restrict__ Wh1,
                              const float* __restrict__ bx,  const float* __restrict__ bh,
                              unsigned short* __restrict__ Wt, float* __restrict__ bias) {
    int t = blockIdx.x * 256 + threadIdx.x;   // 0 .. 512*512-1
    int col = t >> 9, k = t & 511;
    int h = col >> 2, g = col & 3;
    const float* W; int kk;
    if      (k < 128) { W = Wx0; kk = k; }
    else if (k < 256) { W = Wx1; kk = k - 128; }
    else if (k < 384) { W = Wh0; kk = k - 256; }
    else              { W = Wh1; kk = k - 384; }
    float v = W[((size_t)(g << 7) + kk) * 128 + h];
    Wt[(size_t)col * 512 + k] = f2bf(v);
    if (k == 0) bias[col] = bx[(g << 7) + h] + bh[(g << 7) + h];
}

__device__ __forceinline__ f32x4 shflx4(f32x4 v, int m) {
    f32x4 r;
    r[0] = __shfl_xor(v[0], m, 64);
    r[1] = __shfl_xor(v[1], m, 64);
    r[2] = __shfl_xor(v[2], m, 64);
    r[3] = __shfl_xor(v[3], m, 64);
    return r;
}
__device__ __forceinline__ float sel4(f32x4 v, int k) {
    float r = v[0];
    r = (k == 1) ? v[1] : r;
    r = (k == 2) ? v[2] : r;
    r = (k == 3) ? v[3] : r;
    return r;
}
__device__ __forceinline__ float pick4(float a0, float a1, float a2, float a3, int k) {
    float r = a0;
    r = (k == 1) ? a1 : r;
    r = (k == 2) ? a2 : r;
    r = (k == 3) ? a3 : r;
    return r;
}

// GEMM 128x128 tile/block; A staged from XH (kt 0-3, 8-11) or Fp (4-7, 12-15);
// dbuf global_load_lds; register-only LSTM epilogue via shfl_xor gate exchange.
__launch_bounds__(256)
__global__ void gemm_lstm_kernel(const unsigned short* __restrict__ XHu,
                                 const unsigned short* __restrict__ Fpu,
                                 const unsigned short* __restrict__ Wtu,
                                 const float* __restrict__ bias,
                                 const float* __restrict__ c_prev,
                                 float* __restrict__ out) {
    __shared__ __align__(16) short sa[2][128 * 32];
    __shared__ __align__(16) short sb[2][128 * 32];

    const int tid  = threadIdx.x;
    const int lane = tid & 63;
    const int wave = tid >> 6;
    const int wm = wave >> 1, wn = wave & 1;
    const int lr = lane & 15, lq = lane >> 4;

    // XCD co-schedule: blocks {k,k+8,k+16,k+24} share mtile -> same XCD L2.
    const int b = blockIdx.x;                 // 0..3135
    const int ntile = (b >> 3) & 3;
    const int mtile = (b & 7) | ((b >> 5) << 3);
    if (mtile >= 782) return;
    const size_t m0 = (size_t)mtile * 128;
    const int n0 = ntile * 128;

    const short* XH = (const short*)XHu;
    const short* Fp = (const short*)Fpu;
    const short* Wt = (const short*)Wtu;

    // staging addresses: thread t covers A-row t>>2 (+0/64), 16B chunk t&3
    const int arow = tid >> 2;                // 0..63
    const int ak   = (tid & 3) << 3;          // elem offset 0,8,16,24
    const size_t rowA = (m0 + arow) * 256 + ak;      // XH/Fp share row stride 256
    const short* gB0 = Wt + (size_t)(n0 + arow) * 512 + ak;
    const short* gB1 = gB0 + (size_t)64 * 512;

    // c_prev prefetch (registers; latency hidden under the K-loop)
    const int rbase = wm * 64 + lq * 4 + (lr & 3);   // local row this lane outputs
    const int hbase = (n0 >> 2) + wn * 16 + (lr >> 2);
    float cp[4][4];
#pragma unroll
    for (int i = 0; i < 4; ++i) {
        size_t grow = m0 + rbase + i * 16;
#pragma unroll
        for (int j = 0; j < 4; ++j)
            cp[i][j] = (grow < NN) ? c_prev[grow * 128 + hbase + j * 4] : 0.f;
    }
    float bs[4];
#pragma unroll
    for (int j = 0; j < 4; ++j) bs[j] = bias[n0 + wn * 64 + j * 16 + lr];

    // fragment LDS offsets (shorts)
    int offA[4], offB[4];
#pragma unroll
    for (int i = 0; i < 4; ++i) {
        offA[i] = (wm * 64 + i * 16 + lr) * 32 + lq * 8;
        offB[i] = (wn * 64 + i * 16 + lr) * 32 + lq * 8;
    }

    f32x4 acc[4][4];
#pragma unroll
    for (int i = 0; i < 4; ++i)
#pragma unroll
        for (int j = 0; j < 4; ++j) acc[i][j] = (f32x4){0.f, 0.f, 0.f, 0.f};

    auto stage = [&](int kt, int buf) {
        const int off = ((kt >> 3) << 7) + ((kt & 3) << 5);  // col in XH/Fp row
        const short* Ab = ((kt >> 2) & 1) ? Fp : XH;
        gload16(Ab + rowA + off,              &sa[buf][wave * 512]);
        gload16(Ab + rowA + 64 * 256 + off,   &sa[buf][2048 + wave * 512]);
        gload16(gB0 + kt * 32, &sb[buf][wave * 512]);
        gload16(gB1 + kt * 32, &sb[buf][2048 + wave * 512]);
    };

    stage(0, 0);
    for (int kt = 0; kt < 16; ++kt) {
        __syncthreads();                       // staging of buf (kt&1) complete
        if (kt + 1 < 16) stage(kt + 1, (kt + 1) & 1);   // async prefetch
        const int buf = kt & 1;
        bf16x8 af[4], bfr[4];
#pragma unroll
        for (int i = 0; i < 4; ++i) af[i]  = *(const bf16x8*)&sa[buf][offA[i]];
#pragma unroll
        for (int i = 0; i < 4; ++i) bfr[i] = *(const bf16x8*)&sb[buf][offB[i]];
#pragma unroll
        for (int i = 0; i < 4; ++i)
#pragma unroll
            for (int j = 0; j < 4; ++j)
                acc[i][j] = __builtin_amdgcn_mfma_f32_16x16x32_bf16(af[i], bfr[j], acc[i][j], 0, 0, 0);
    }

    // Register-only LSTM epilogue. C/D: col=lane&15 (=lr), row=lq*4+reg.
    // col = 4*h_local+g -> the 4 gates of (row,h) live in lanes lr&~3 .. |3.
    // 3-step shfl_xor butterfly gives each lane all 4 gates; lane k=lr&3
    // takes row component k.
    const int k = lr & 3;
#pragma unroll
    for (int i = 0; i < 4; ++i) {
        size_t grow = m0 + rbase + i * 16;
        if (grow >= NN) continue;
#pragma unroll
        for (int j = 0; j < 4; ++j) {
            f32x4 v0 = acc[i][j];
            v0[0] += bs[j]; v0[1] += bs[j]; v0[2] += bs[j]; v0[3] += bs[j];
            f32x4 v1 = shflx4(v0, 1);
            f32x4 v2 = shflx4(v0, 2);
            f32x4 v3 = shflx4(v0, 3);
            // vv[m] = gate (k^m), row k
            float vv0 = sel4(v0, k), vv1 = sel4(v1, k),
                  vv2 = sel4(v2, k), vv3 = sel4(v3, k);
            float gi = pick4(vv0, vv1, vv2, vv3, k);       // gate 0 (i)
            float gf = pick4(vv0, vv1, vv2, vv3, k ^ 1);   // gate 1 (f)
            float gg = pick4(vv0, vv1, vv2, vv3, k ^ 2);   // gate 2 (g)
            float go = pick4(vv0, vv1, vv2, vv3, k ^ 3);   // gate 3 (o)
            float iv = sigf(gi), fv = sigf(gf), gv = tanhf_(gg), ov = sigf(go);
            float ct = fv * cp[i][j] + iv * gv;
            float ht = ov * tanhf_(ct);
            int h = hbase + j * 4;
            out[grow * 128 + h] = ht;
            out[(size_t)NN * 128 + grow * 128 + h] = ct;
        }
    }
}

extern "C" void kernel_launch(void* const* d_in, const int* in_sizes, int n_in,
                              void* d_out, int out_size, void* d_ws, size_t ws_size,
                              hipStream_t stream) {
    const float* x      = (const float*)d_in[0];
    const int*   ei     = (const int*)  d_in[1];
    const float* ew     = (const float*)d_in[2];
    const float* h_prev = (const float*)d_in[3];
    const float* c_prev = (const float*)d_in[4];
    const float* Wx0    = (const float*)d_in[5];
    const float* Wx1    = (const float*)d_in[6];
    const float* Wh0    = (const float*)d_in[7];
    const float* Wh1    = (const float*)d_in[8];
    const float* bx     = (const float*)d_in[9];
    const float* bh     = (const float*)d_in[10];
    float* out = (float*)d_out;

    char* ws = (char*)d_ws;
    float*          deg    = (float*)(ws + OFF_DEG);
    int*            cnt    = (int*)  (ws + OFF_CNT);
    int*            cursor = (int*)  (ws + OFF_CUR);
    int*            rowptr = (int*)  (ws + OFF_ROWPTR);
    int*            bsum   = (int*)  (ws + OFF_BSUM);
    uint2*          csr    = (uint2*)(ws + OFF_CSR);
    unsigned short* XH     = (unsigned short*)(ws + OFF_XH);
    unsigned short* Fp     = (unsigned short*)(ws + OFF_FP);
    unsigned short* Wt     = (unsigned short*)(ws + OFF_WT);
    float*          bias   = (float*)(ws + OFF_BIAS);

    const int* src = ei;
    const int* dst = ei + NE;

    // zero deg+cnt+cursor (contiguous, 1,201,152 B = 75,072 float4)
    zero_kernel<<<(75072 + 255) / 256, 256, 0, stream>>>((float4*)ws, 75072);

    deg_hist_kernel<<<NE / 256, 256, 0, stream>>>(src, dst, ew, deg, cnt);
    scan_part_kernel<<<98, 1024, 0, stream>>>(cnt, rowptr, bsum);
    scan_top_kernel<<<1, 64, 0, stream>>>(bsum, rowptr);
    scan_add_kernel<<<98, 1024, 0, stream>>>(bsum, rowptr);
    fill_kernel<<<NE / 256, 256, 0, stream>>>(src, dst, ew, deg, rowptr, cursor, csr);

    cvt_kernel<<<MPAD * 64 / 256, 256, 0, stream>>>(x, h_prev, XH);
    gather_pack_kernel<<<MPAD / 4, 256, 0, stream>>>(rowptr, csr, XH, Fp);
    pack_w_kernel<<<512 * 512 / 256, 256, 0, stream>>>(Wx0, Wx1, Wh0, Wh1, bx, bh, Wt, bias);

    gemm_lstm_kernel<<<3136, 256, 0, stream>>>(XH, Fp, Wt, bias, c_prev, out);
}